// Round 4
// baseline (282.194 us; speedup 1.0000x reference)
//
#include <hip/hip_runtime.h>

// B=4, P=12000, C=64, NX=NY=512
//   in[0]: pillar_embeddings float32 [B,P,C]
//   in[1]: pillar_coords     int32   [B,P,2]  (ix, iy)
//   in[2]: pillar_mask       int32   [B,P]
//   out:   float32 [B, C, NY, NX]
//
// Round-4 theory: rounds 0/2/3 (and round-1's pure zero-fill) ALL ran the
// 256 MB store stream at ~2.5 TB/s despite completely different address
// patterns and load structures. Common factor: __builtin_nontemporal_store.
// The rocclr fill (plain stores) hits 6.35 TB/s on the same chip. Conclusion:
// the nt flag (write-through / no-allocate) caps streaming store throughput
// at ~2.5 TB/s on gfx950 by defeating L2 write-back aggregation.
// Fix: PLAIN stores, sequential order (round-3 layout). Since plain stores
// churn L2 and evict the map, each thread now produces 4 consecutive
// channels from ONE map entry (map re-read 256->64 MB, L3-resident), with
// vectorized float4 emb loads (channels c..c+3 are contiguous per pillar).
#define NXc 512
#define NYc 512
#define Bc  4
#define Pc  12000
#define Cc  64
#define CELLS (NXc * NYc)            // 262144 cells per batch (2^18)
#define MAPN  (Bc * CELLS)           // 1,048,576 map entries (4 MB)
#define OUT_FV4 (Bc * Cc * (CELLS / 4))   // 16,777,216 float4 (256 MB)
#define PLANE4 (CELLS / 4)           // 65536 fv4 per c-plane

typedef float fv4 __attribute__((ext_vector_type(4)));
typedef int   iv4 __attribute__((ext_vector_type(4)));

__global__ void map_scatter_kernel(const int* __restrict__ coords,
                                   const int* __restrict__ mask,
                                   int* __restrict__ map) {
    const int p = blockIdx.x * blockDim.x + threadIdx.x;   // global pillar id
    if (p >= Bc * Pc) return;
    if (mask[p] <= 0) return;
    const int ix = coords[2 * p];
    const int iy = coords[2 * p + 1];
    const int b = p / Pc;
    map[b * CELLS + iy * NXc + ix] = p;    // cells unique per batch -> no race
}

// One thread per (4-channel group, 4-cell group): t = (b*16 + cg)*PLANE4 + cell4.
// Produces out planes c = 4*cg .. 4*cg+3 at this cell4. Plain (cached) stores.
__global__ void __launch_bounds__(256)
bev_gather4_kernel(const float* __restrict__ emb,
                   const iv4* __restrict__ map4,
                   fv4* __restrict__ out4) {
    const int t     = blockIdx.x * blockDim.x + threadIdx.x;  // 0..OUT_FV4/4
    const int cell4 = t & (PLANE4 - 1);          // 0..65535
    const int pg    = t >> 16;                   // b*16 + cg
    const int cg    = pg & 15;                   // channel group 0..15
    const int b     = pg >> 4;                   // batch 0..3

    // coalesced 16B/lane map read; 64 MB total re-read, L3-resident
    const iv4 m = map4[(size_t)b * PLANE4 + cell4];

    // clamped vector gathers: 16B per cell, channels 4*cg .. 4*cg+3.
    // Empty lanes (95%) read the broadcast pillar-0 line and get zeroed.
    const float* eb = emb + cg * 4;
    const fv4 ex = *(const fv4*)(eb + (size_t)(m.x < 0 ? 0 : m.x) * Cc);
    const fv4 ey = *(const fv4*)(eb + (size_t)(m.y < 0 ? 0 : m.y) * Cc);
    const fv4 ez = *(const fv4*)(eb + (size_t)(m.z < 0 ? 0 : m.z) * Cc);
    const fv4 ew = *(const fv4*)(eb + (size_t)(m.w < 0 ? 0 : m.w) * Cc);

    // transpose cells<->channels in registers (scalar selects)
    fv4 v0, v1, v2, v3;
    v0.x = (m.x >= 0) ? ex.x : 0.f;  v1.x = (m.x >= 0) ? ex.y : 0.f;
    v2.x = (m.x >= 0) ? ex.z : 0.f;  v3.x = (m.x >= 0) ? ex.w : 0.f;
    v0.y = (m.y >= 0) ? ey.x : 0.f;  v1.y = (m.y >= 0) ? ey.y : 0.f;
    v2.y = (m.y >= 0) ? ey.z : 0.f;  v3.y = (m.y >= 0) ? ey.w : 0.f;
    v0.z = (m.z >= 0) ? ez.x : 0.f;  v1.z = (m.z >= 0) ? ez.y : 0.f;
    v2.z = (m.z >= 0) ? ez.z : 0.f;  v3.z = (m.z >= 0) ? ez.w : 0.f;
    v0.w = (m.w >= 0) ? ew.x : 0.f;  v1.w = (m.w >= 0) ? ew.y : 0.f;
    v2.w = (m.w >= 0) ? ew.z : 0.f;  v3.w = (m.w >= 0) ? ew.w : 0.f;

    // 4 plain fv4 stores, plane stride apart; wave-level each is 1 KB
    // contiguous; block-level 4 interleaved sequential streams.
    fv4* op = out4 + ((size_t)(b * Cc + cg * 4)) * PLANE4 + cell4;
    op[0 * PLANE4] = v0;
    op[1 * PLANE4] = v1;
    op[2 * PLANE4] = v2;
    op[3 * PLANE4] = v3;
}

extern "C" void kernel_launch(void* const* d_in, const int* in_sizes, int n_in,
                              void* d_out, int out_size, void* d_ws, size_t ws_size,
                              hipStream_t stream) {
    const float* emb  = (const float*)d_in[0];
    const int* coords = (const int*)d_in[1];
    const int* mask   = (const int*)d_in[2];
    float* out        = (float*)d_out;
    int* map          = (int*)d_ws;          // 4 MB scratch

    hipMemsetAsync(map, 0xFF, (size_t)MAPN * sizeof(int), stream);  // -1 fill
    map_scatter_kernel<<<(Bc * Pc + 255) / 256, 256, 0, stream>>>(coords, mask, map);
    bev_gather4_kernel<<<OUT_FV4 / 4 / 256, 256, 0, stream>>>(emb, (const iv4*)map,
                                                              (fv4*)out);
}